// Round 9
// baseline (173.038 us; speedup 1.0000x reference)
//
#include <hip/hip_runtime.h>
#include <hip/hip_bf16.h>
#include <stdint.h>

// SimpleOrdinalLinearDecayEmbedding: out[m,d] = gate[m] * (q[m,:]@Wq[d,:]) + bq[d]
// gate[m] = sigmoid(sum_k max(1-|k-r[m]|/3,0)*Wr[k] + br), r in {0..3} -> LUT.
// M = 32768, K = 800, N = 64.
//
// Model so far: aggregate VMEM bytes / time ~ 6.8 TB/s (R4: 512MB/75us, R7:
// 310MB/47us). R8 (156 MB, flat 48us) likely broke on register pressure
// (DEPTH3 x 4-tile stages ~250 VGPR -> spills/codegen).
//
// R9: B leaves the VMEM stream. Block = 256 thr (4 waves = 2 row-groups x 2
// K-halves), 128 rows/block, grid 256 (1 block/CU, LDS 100 KB). B blob staged
// to LDS once (global_load_lds x25/wave + ONE syncthreads), K-loop reads B via
// ds_read_b128 (contiguous, conflict-free) -> no in-loop barriers. A uses R7's
// register pipeline, DEPTH=2, 4 row-tiles/wave (~190 VGPR, no spill at
// launch_bounds(256,2)). VMEM ~ 105(A) + 25.6(B) + 8(out) = 139 MB -> ~21-23us.

#define QD 800
#define DD 64
#define M_TOTAL 32768
#define KT 25      // 800 / 32
#define KH0 13     // khalf0: kt 0..12
#define KH1 12     // khalf1: kt 13..24
#define DEPTH 2

typedef __attribute__((ext_vector_type(8))) short bf16x8;
typedef __attribute__((ext_vector_type(4))) float f32x4;

typedef const __attribute__((address_space(1))) uint32_t* gas1_u32;
typedef __attribute__((address_space(3))) uint32_t* las3_u32;

static __device__ __forceinline__ void gll16(const void* g, const void* l) {
  // LDS dest = wave-uniform base + lane*16 (HW rule m104/m108; mechanics
  // validated in R6 which passed correctness with this helper).
  __builtin_amdgcn_global_load_lds((gas1_u32)(uintptr_t)g,
                                   (las3_u32)(uint32_t)(uintptr_t)l, 16, 0, 0);
}

static __device__ __forceinline__ short f2bf(float f) {
  union { __hip_bfloat16 h; short s; } u;
  u.h = __float2bfloat16(f);
  return u.s;
}

static __device__ __forceinline__ bf16x8 pack8(f32x4 lo, f32x4 hi) {
  bf16x8 r;
  r[0] = f2bf(lo.x); r[1] = f2bf(lo.y); r[2] = f2bf(lo.z); r[3] = f2bf(lo.w);
  r[4] = f2bf(hi.x); r[5] = f2bf(hi.y); r[6] = f2bf(hi.z); r[7] = f2bf(hi.w);
  return r;
}

// sigma(lhi,j) = (j<4 ? lhi*4+j : 16+lhi*4+j-4): lo ksegs at +0, hi at +16 floats.
static __device__ __forceinline__ bf16x8 load_split8(const float* __restrict__ p) {
  return pack8(*reinterpret_cast<const f32x4*>(p),
               *reinterpret_cast<const f32x4*>(p + 16));
}

// Prep: B blob. Chunk idx = (kt*4 + c)*64 + lane holds the 8 bf16 B-fragment
// values for (kt, c, lane): Wq[c*16+(lane&15)][kt*32+sigma]. 100 KB.
__global__ void convert_wq_kernel(const float* __restrict__ Wq, short* __restrict__ Bb) {
  int idx = blockIdx.x * 256 + threadIdx.x;  // 6400 threads
  int kt = idx >> 8;
  int c = (idx >> 6) & 3;
  int lane = idx & 63;
  int l15 = lane & 15, lhi = lane >> 4;
  const float* p = Wq + (c * 16 + l15) * QD + kt * 32 + lhi * 4;
  *reinterpret_cast<bf16x8*>(Bb + (size_t)idx * 8) = load_split8(p);
}

// K-loop over CNT tiles (global kt = ktbase+i). A: DEPTH=2 register pipeline.
// B: ds_read_b128 from LDS, one-ahead prefetch. No barriers.
template <int CNT>
static __device__ __forceinline__ void kh_loop(
    const float* __restrict__ a0, const float* __restrict__ a1,
    const float* __restrict__ a2, const float* __restrict__ a3,
    const short* __restrict__ bb,  // = Bs + ktbase*2048 + lane*8 (shorts)
    f32x4 (&acc)[4][4]) {
  f32x4 sLo[DEPTH][4], sHi[DEPTH][4];
  bf16x8 bB[2][4];

#pragma unroll
  for (int s = 0; s < DEPTH; ++s) {
    sLo[s][0] = *reinterpret_cast<const f32x4*>(a0 + s * 32);
    sHi[s][0] = *reinterpret_cast<const f32x4*>(a0 + s * 32 + 16);
    sLo[s][1] = *reinterpret_cast<const f32x4*>(a1 + s * 32);
    sHi[s][1] = *reinterpret_cast<const f32x4*>(a1 + s * 32 + 16);
    sLo[s][2] = *reinterpret_cast<const f32x4*>(a2 + s * 32);
    sHi[s][2] = *reinterpret_cast<const f32x4*>(a2 + s * 32 + 16);
    sLo[s][3] = *reinterpret_cast<const f32x4*>(a3 + s * 32);
    sHi[s][3] = *reinterpret_cast<const f32x4*>(a3 + s * 32 + 16);
  }
#pragma unroll
  for (int c = 0; c < 4; ++c)
    bB[0][c] = *reinterpret_cast<const bf16x8*>(bb + c * 512);

#pragma unroll
  for (int i = 0; i < CNT; ++i) {
    const int s = i & 1;
    // Prefetch next kt's B frags from LDS (hides ~120cyc lgkm latency).
    if (i + 1 < CNT) {
#pragma unroll
      for (int c = 0; c < 4; ++c)
        bB[(i + 1) & 1][c] =
            *reinterpret_cast<const bf16x8*>(bb + (i + 1) * 2048 + c * 512);
    }
    bf16x8 af0 = pack8(sLo[s][0], sHi[s][0]);
    bf16x8 af1 = pack8(sLo[s][1], sHi[s][1]);
    bf16x8 af2 = pack8(sLo[s][2], sHi[s][2]);
    bf16x8 af3 = pack8(sLo[s][3], sHi[s][3]);
#pragma unroll
    for (int c = 0; c < 4; ++c) {
      acc[0][c] = __builtin_amdgcn_mfma_f32_16x16x32_bf16(af0, bB[i & 1][c], acc[0][c], 0, 0, 0);
      acc[1][c] = __builtin_amdgcn_mfma_f32_16x16x32_bf16(af1, bB[i & 1][c], acc[1][c], 0, 0, 0);
      acc[2][c] = __builtin_amdgcn_mfma_f32_16x16x32_bf16(af2, bB[i & 1][c], acc[2][c], 0, 0, 0);
      acc[3][c] = __builtin_amdgcn_mfma_f32_16x16x32_bf16(af3, bB[i & 1][c], acc[3][c], 0, 0, 0);
    }
    // Refill A stage s with tile i+2.
    if (i + DEPTH < CNT) {
      sLo[s][0] = *reinterpret_cast<const f32x4*>(a0 + (i + DEPTH) * 32);
      sHi[s][0] = *reinterpret_cast<const f32x4*>(a0 + (i + DEPTH) * 32 + 16);
      sLo[s][1] = *reinterpret_cast<const f32x4*>(a1 + (i + DEPTH) * 32);
      sHi[s][1] = *reinterpret_cast<const f32x4*>(a1 + (i + DEPTH) * 32 + 16);
      sLo[s][2] = *reinterpret_cast<const f32x4*>(a2 + (i + DEPTH) * 32);
      sHi[s][2] = *reinterpret_cast<const f32x4*>(a2 + (i + DEPTH) * 32 + 16);
      sLo[s][3] = *reinterpret_cast<const f32x4*>(a3 + (i + DEPTH) * 32);
      sHi[s][3] = *reinterpret_cast<const f32x4*>(a3 + (i + DEPTH) * 32 + 16);
    }
    __builtin_amdgcn_sched_barrier(0);  // pin the modulo schedule (R7-proven)
  }
}

// 256 blocks x 256 thr; wave = (rt = row-group, kh = K-half). 128 rows/block.
__global__ __launch_bounds__(256, 2) void sold_kernel(
    const float* __restrict__ q, const int* __restrict__ rdat,
    const short* __restrict__ Bb, const float* __restrict__ bq,
    const float* __restrict__ Wr, const float* __restrict__ br,
    float* __restrict__ out) {
  const int t = threadIdx.x;
  const int lane = t & 63;
  const int wave = t >> 6;
  const int rt = wave & 1;
  const int kh = wave >> 1;
  const int l15 = lane & 15;
  const int lhi = lane >> 4;
  const int m0 = blockIdx.x * 128;

  __shared__ __align__(16) char smem[102400];  // B blob (100 KB); reused for combine
  short* Bs = (short*)smem;

  // Stage blob -> LDS: wave stages chunks iter*256 + wave*64 + lane (16 B each).
#pragma unroll 5
  for (int iter = 0; iter < 25; ++iter) {
    int chunk = iter * 256 + wave * 64;  // wave-uniform
    gll16(Bb + (size_t)(chunk + lane) * 8, Bs + (size_t)chunk * 8);
  }
  __syncthreads();  // drains gll16; blob resident for the whole K-loop

  const int kt0 = kh ? KH0 : 0;
  const int rowb = m0 + rt * 64 + l15;
  const float* a0 = q + (size_t)(rowb +  0) * QD + kt0 * 32 + lhi * 4;
  const float* a1 = q + (size_t)(rowb + 16) * QD + kt0 * 32 + lhi * 4;
  const float* a2 = q + (size_t)(rowb + 32) * QD + kt0 * 32 + lhi * 4;
  const float* a3 = q + (size_t)(rowb + 48) * QD + kt0 * 32 + lhi * 4;
  const short* bb = Bs + (size_t)kt0 * 2048 + lane * 8;

  f32x4 acc[4][4];
#pragma unroll
  for (int t4 = 0; t4 < 4; ++t4)
#pragma unroll
    for (int c = 0; c < 4; ++c) acc[t4][c] = {0.f, 0.f, 0.f, 0.f};

  if (kh == 0) {
    kh_loop<KH0>(a0, a1, a2, a3, bb, acc);
  } else {
    kh_loop<KH1>(a0, a1, a2, a3, bb, acc);
  }

  // K-split combine; comb reuses the B LDS region (B dead after this barrier).
  __syncthreads();
  float* comb = (float*)smem;  // [rt][t4][c*4+r][lane] = 2*4*16*64 f32 = 32 KB
  if (kh == 1) {
#pragma unroll
    for (int t4 = 0; t4 < 4; ++t4)
#pragma unroll
      for (int c = 0; c < 4; ++c)
#pragma unroll
        for (int r = 0; r < 4; ++r)
          comb[(((rt * 4 + t4) * 16) + c * 4 + r) * 64 + lane] = acc[t4][c][r];
  }
  __syncthreads();
  if (kh == 1) return;

#pragma unroll
  for (int t4 = 0; t4 < 4; ++t4)
#pragma unroll
    for (int c = 0; c < 4; ++c)
#pragma unroll
      for (int r = 0; r < 4; ++r)
        acc[t4][c][r] += comb[(((rt * 4 + t4) * 16) + c * 4 + r) * 64 + lane];

  // Gate LUT: r in {0..3}; weights w[k] = max(1-|k-r|/3, 0).
  float wr[4] = {Wr[0], Wr[1], Wr[2], Wr[3]};
  float brv = br[0];
  float lut[4];
  const float inv3 = 1.0f / 3.0f;
#pragma unroll
  for (int r = 0; r < 4; ++r) {
    float s = brv;
#pragma unroll
    for (int k = 0; k < 4; ++k)
      s += fmaxf(1.0f - fabsf((float)(k - r)) * inv3, 0.0f) * wr[k];
    lut[r] = 1.0f / (1.0f + __expf(-s));
  }

  float bqv[4];
#pragma unroll
  for (int c = 0; c < 4; ++c) bqv[c] = bq[c * 16 + l15];

  // D layout (HW-verified m89): col = lane&15 (+16 per c), row = (lane>>4)*4 + r.
#pragma unroll
  for (int t4 = 0; t4 < 4; ++t4) {
#pragma unroll
    for (int r = 0; r < 4; ++r) {
      int row = m0 + rt * 64 + t4 * 16 + lhi * 4 + r;
      float g = lut[rdat[row]];
      float* orow = out + (size_t)row * DD + l15;
#pragma unroll
      for (int c = 0; c < 4; ++c) orow[c * 16] = acc[t4][c][r] * g + bqv[c];
    }
  }
}

// Fallback (ws too small — not expected): R4-style direct from fp32 Wq.
__global__ __launch_bounds__(256, 2) void sold_direct(
    const float* __restrict__ q, const int* __restrict__ rdat,
    const float* __restrict__ Wq, const float* __restrict__ bq,
    const float* __restrict__ Wr, const float* __restrict__ br,
    float* __restrict__ out) {
  const int lane = threadIdx.x & 63;
  const int wave = threadIdx.x >> 6;
  const int l15 = lane & 15;
  const int lhi = lane >> 4;
  const int m0 = blockIdx.x * 64 + wave * 16;
  const float* aptr = q + (size_t)(m0 + l15) * QD + lhi * 4;
  const float* w0 = Wq + (0 * 16 + l15) * QD + lhi * 4;
  const float* w1 = Wq + (1 * 16 + l15) * QD + lhi * 4;
  const float* w2 = Wq + (2 * 16 + l15) * QD + lhi * 4;
  const float* w3 = Wq + (3 * 16 + l15) * QD + lhi * 4;
  f32x4 acc0 = {0.f,0.f,0.f,0.f}, acc1 = {0.f,0.f,0.f,0.f};
  f32x4 acc2 = {0.f,0.f,0.f,0.f}, acc3 = {0.f,0.f,0.f,0.f};
#pragma unroll 5
  for (int kt = 0; kt < KT; ++kt) {
    bf16x8 a  = load_split8(aptr + kt * 32);
    bf16x8 b0 = load_split8(w0 + kt * 32);
    bf16x8 b1 = load_split8(w1 + kt * 32);
    bf16x8 b2 = load_split8(w2 + kt * 32);
    bf16x8 b3 = load_split8(w3 + kt * 32);
    acc0 = __builtin_amdgcn_mfma_f32_16x16x32_bf16(a, b0, acc0, 0, 0, 0);
    acc1 = __builtin_amdgcn_mfma_f32_16x16x32_bf16(a, b1, acc1, 0, 0, 0);
    acc2 = __builtin_amdgcn_mfma_f32_16x16x32_bf16(a, b2, acc2, 0, 0, 0);
    acc3 = __builtin_amdgcn_mfma_f32_16x16x32_bf16(a, b3, acc3, 0, 0, 0);
  }
  float wr[4] = {Wr[0], Wr[1], Wr[2], Wr[3]};
  float brv = br[0], lut[4];
  const float inv3 = 1.0f / 3.0f;
#pragma unroll
  for (int r = 0; r < 4; ++r) {
    float s = brv;
#pragma unroll
    for (int k = 0; k < 4; ++k)
      s += fmaxf(1.0f - fabsf((float)(k - r)) * inv3, 0.0f) * wr[k];
    lut[r] = 1.0f / (1.0f + __expf(-s));
  }
  float bqv0 = bq[l15], bqv1 = bq[16 + l15], bqv2 = bq[32 + l15], bqv3 = bq[48 + l15];
#pragma unroll
  for (int r = 0; r < 4; ++r) {
    int row = m0 + lhi * 4 + r;
    float g = lut[rdat[row]];
    float* orow = out + (size_t)row * DD + l15;
    orow[0]  = acc0[r] * g + bqv0;
    orow[16] = acc1[r] * g + bqv1;
    orow[32] = acc2[r] * g + bqv2;
    orow[48] = acc3[r] * g + bqv3;
  }
}

extern "C" void kernel_launch(void* const* d_in, const int* in_sizes, int n_in,
                              void* d_out, int out_size, void* d_ws, size_t ws_size,
                              hipStream_t stream) {
  const float* q    = (const float*)d_in[0];  // [64,512,800] f32
  const int*   rdat = (const int*)d_in[1];    // [64,512] i32
  const float* Wq   = (const float*)d_in[2];  // [64,800] f32
  const float* bq   = (const float*)d_in[3];  // [64] f32
  const float* Wr   = (const float*)d_in[4];  // [1,4] f32
  const float* br   = (const float*)d_in[5];  // [1] f32
  float* out = (float*)d_out;                 // [64,512,64] f32

  const size_t need_ws = (size_t)KT * 2048 * sizeof(short);  // 102400 B
  if (ws_size >= need_ws) {
    short* Bb = (short*)d_ws;
    convert_wq_kernel<<<KT, 256, 0, stream>>>(Wq, Bb);
    sold_kernel<<<M_TOTAL / 128, 256, 0, stream>>>(q, rdat, Bb, bq, Wr, br, out);
  } else {
    sold_direct<<<M_TOTAL / 64, 256, 0, stream>>>(q, rdat, Wq, bq, Wr, br, out);
  }
}